// Round 1
// baseline (1150.772 us; speedup 1.0000x reference)
//
#include <hip/hip_runtime.h>

// GConv: out = spmm(A0, x@W) + spmm(A1, x@W) + bias
// N=100000, E=600000, F_IN=F_OUT=128 (hardcoded feature dim).

#define FDIM 128

// ---------------- GEMM: support = x @ W ----------------
// tile: 64 nodes x 64 outputs per block; grid = (ceil(n/64), 2)
__global__ __launch_bounds__(256) void gemm_xw(const float* __restrict__ x,
                                               const float* __restrict__ w,
                                               float* __restrict__ support, int n) {
    __shared__ float xs[64][132];   // +4 pad breaks bank aliasing on column reads
    __shared__ float ws[128][68];
    const int tid = threadIdx.x;
    const int m0 = blockIdx.x * 64;
    const int j0 = blockIdx.y * 64;

    // stage W half-tile: ws[k][c] = w[k][j0+c], 128x64 floats
    for (int idx = tid * 4; idx < 128 * 64; idx += 256 * 4) {
        int k = idx >> 6;
        int c = idx & 63;
        float4 v = *(const float4*)(w + k * FDIM + j0 + c);
        ws[k][c] = v.x; ws[k][c + 1] = v.y; ws[k][c + 2] = v.z; ws[k][c + 3] = v.w;
    }
    // stage x tile: xs[r][c] = x[m0+r][c], 64x128 floats
    for (int idx = tid * 4; idx < 64 * 128; idx += 256 * 4) {
        int r = idx >> 7;
        int c = idx & 127;
        float4 v = make_float4(0.f, 0.f, 0.f, 0.f);
        if (m0 + r < n) v = *(const float4*)(x + (size_t)(m0 + r) * FDIM + c);
        xs[r][c] = v.x; xs[r][c + 1] = v.y; xs[r][c + 2] = v.z; xs[r][c + 3] = v.w;
    }
    __syncthreads();

    const int tx = tid & 15;   // output group: j = j0 + tx*4 + 0..3
    const int ty = tid >> 4;   // node group:   m = m0 + ty*4 + 0..3
    float acc[4][4] = {};
    #pragma unroll 4
    for (int k = 0; k < 128; ++k) {
        float4 wv = *(const float4*)&ws[k][tx * 4];
        float xv[4];
        #pragma unroll
        for (int i = 0; i < 4; ++i) xv[i] = xs[ty * 4 + i][k];
        #pragma unroll
        for (int i = 0; i < 4; ++i) {
            acc[i][0] += xv[i] * wv.x;
            acc[i][1] += xv[i] * wv.y;
            acc[i][2] += xv[i] * wv.z;
            acc[i][3] += xv[i] * wv.w;
        }
    }
    #pragma unroll
    for (int i = 0; i < 4; ++i) {
        int m = m0 + ty * 4 + i;
        if (m < n) {
            float4 v = make_float4(acc[i][0], acc[i][1], acc[i][2], acc[i][3]);
            *(float4*)(support + (size_t)m * FDIM + j0 + tx * 4) = v;
        }
    }
}

// ---------------- out[i][:] = bias[:] ----------------
__global__ __launch_bounds__(256) void init_bias(const float* __restrict__ bias,
                                                 float* __restrict__ out, int n) {
    int idx = blockIdx.x * 256 + threadIdx.x;   // one float4 per thread
    int total = n * (FDIM / 4);
    if (idx < total) {
        int j = (idx & (FDIM / 4 - 1)) * 4;
        float4 b = *(const float4*)(bias + j);
        *(float4*)(out + (size_t)idx * 4) = b;
    }
}

// ---------------- scatter: out[r] += v * support[c] over both edge sets -----
// 64 lanes per edge, 2 floats per lane.
__global__ __launch_bounds__(256) void scatter_edges(
    const float* __restrict__ support,
    const int* __restrict__ rows0, const int* __restrict__ cols0, const float* __restrict__ vals0,
    const int* __restrict__ rows1, const int* __restrict__ cols1, const float* __restrict__ vals1,
    float* __restrict__ out, int E) {
    int gid = blockIdx.x * 256 + threadIdx.x;
    int lane = gid & 63;
    int eg = gid >> 6;
    if (eg >= 2 * E) return;
    const int* rows; const int* cols; const float* vals; int e;
    if (eg < E) { e = eg;     rows = rows0; cols = cols0; vals = vals0; }
    else        { e = eg - E; rows = rows1; cols = cols1; vals = vals1; }
    int r = rows[e];
    int c = cols[e];
    float v = vals[e];
    float2 s = *(const float2*)(support + (size_t)c * FDIM + lane * 2);
    float* op = out + (size_t)r * FDIM + lane * 2;
    atomicAdd(op,     s.x * v);
    atomicAdd(op + 1, s.y * v);
}

extern "C" void kernel_launch(void* const* d_in, const int* in_sizes, int n_in,
                              void* d_out, int out_size, void* d_ws, size_t ws_size,
                              hipStream_t stream) {
    const float* x     = (const float*)d_in[0];
    const float* w     = (const float*)d_in[1];
    const float* bias  = (const float*)d_in[2];
    const float* vals0 = (const float*)d_in[3];
    const float* vals1 = (const float*)d_in[4];
    const int*   rows0 = (const int*)d_in[5];
    const int*   cols0 = (const int*)d_in[6];
    const int*   rows1 = (const int*)d_in[7];
    const int*   cols1 = (const int*)d_in[8];
    const int n = in_sizes[0] / FDIM;
    const int E = in_sizes[3];
    float* support = (float*)d_ws;    // n*128 floats = 51.2 MB
    float* out = (float*)d_out;

    dim3 ggrid((n + 63) / 64, 2);
    gemm_xw<<<ggrid, 256, 0, stream>>>(x, w, support, n);

    int total4 = n * (FDIM / 4);
    init_bias<<<(total4 + 255) / 256, 256, 0, stream>>>(bias, out, n);

    long long tthreads = 2LL * E * 64;
    int blocks = (int)((tthreads + 255) / 256);
    scatter_edges<<<blocks, 256, 0, stream>>>(support, rows0, cols0, vals0,
                                              rows1, cols1, vals1, out, E);
}

// Round 2
// 622.471 us; speedup vs baseline: 1.8487x; 1.8487x over previous
//
#include <hip/hip_runtime.h>

// GConv: out = spmm(A0, S) + spmm(A1, S) + bias,  S = x @ W
// N=100000, E=600000, F_IN=F_OUT=128.
// Pull-mode SpMM: build CSR (by destination row) on device, then one wave
// per output row accumulates in registers -> single plain store. No fp atomics.

#define FDIM 128

// ---------------- GEMM: support = x @ W ----------------
__global__ __launch_bounds__(256) void gemm_xw(const float* __restrict__ x,
                                               const float* __restrict__ w,
                                               float* __restrict__ support, int n) {
    __shared__ float xs[64][132];
    __shared__ float ws[128][68];
    const int tid = threadIdx.x;
    const int m0 = blockIdx.x * 64;
    const int j0 = blockIdx.y * 64;

    for (int idx = tid * 4; idx < 128 * 64; idx += 256 * 4) {
        int k = idx >> 6;
        int c = idx & 63;
        float4 v = *(const float4*)(w + k * FDIM + j0 + c);
        ws[k][c] = v.x; ws[k][c + 1] = v.y; ws[k][c + 2] = v.z; ws[k][c + 3] = v.w;
    }
    for (int idx = tid * 4; idx < 64 * 128; idx += 256 * 4) {
        int r = idx >> 7;
        int c = idx & 127;
        float4 v = make_float4(0.f, 0.f, 0.f, 0.f);
        if (m0 + r < n) v = *(const float4*)(x + (size_t)(m0 + r) * FDIM + c);
        xs[r][c] = v.x; xs[r][c + 1] = v.y; xs[r][c + 2] = v.z; xs[r][c + 3] = v.w;
    }
    __syncthreads();

    const int tx = tid & 15;
    const int ty = tid >> 4;
    float acc[4][4] = {};
    #pragma unroll 4
    for (int k = 0; k < 128; ++k) {
        float4 wv = *(const float4*)&ws[k][tx * 4];
        float xv[4];
        #pragma unroll
        for (int i = 0; i < 4; ++i) xv[i] = xs[ty * 4 + i][k];
        #pragma unroll
        for (int i = 0; i < 4; ++i) {
            acc[i][0] += xv[i] * wv.x;
            acc[i][1] += xv[i] * wv.y;
            acc[i][2] += xv[i] * wv.z;
            acc[i][3] += xv[i] * wv.w;
        }
    }
    #pragma unroll
    for (int i = 0; i < 4; ++i) {
        int m = m0 + ty * 4 + i;
        if (m < n) {
            float4 v = make_float4(acc[i][0], acc[i][1], acc[i][2], acc[i][3]);
            *(float4*)(support + (size_t)m * FDIM + j0 + tx * 4) = v;
        }
    }
}

// ---------------- CSR build step 1: histogram of destination rows ----------
__global__ __launch_bounds__(256) void hist_rows(const int* __restrict__ rows0,
                                                 const int* __restrict__ rows1,
                                                 int* __restrict__ counts, int E) {
    int gid = blockIdx.x * 256 + threadIdx.x;
    if (gid < E)          atomicAdd(&counts[rows0[gid]], 1);
    else if (gid < 2 * E) atomicAdd(&counts[rows1[gid - E]], 1);
}

// ---------------- step 2: exclusive scan (single block, 1024 threads) ------
__global__ __launch_bounds__(1024) void scan_counts(const int* __restrict__ counts,
                                                    int* __restrict__ rowptr,
                                                    int* __restrict__ cursor, int n) {
    __shared__ int partial[1024];
    const int t = threadIdx.x;
    const int CH = (n + 1023) >> 10;
    const int s = t * CH;
    const int e = min(s + CH, n);
    int sum = 0;
    for (int i = s; i < e; ++i) sum += counts[i];
    partial[t] = sum;
    __syncthreads();
    // Hillis-Steele inclusive scan
    for (int d = 1; d < 1024; d <<= 1) {
        int v = (t >= d) ? partial[t - d] : 0;
        __syncthreads();
        partial[t] += v;
        __syncthreads();
    }
    int run = (t == 0) ? 0 : partial[t - 1];
    for (int i = s; i < e; ++i) {
        rowptr[i] = run;
        cursor[i] = run;
        run += counts[i];
    }
    if (t == 1023) rowptr[n] = partial[1023];
}

// ---------------- step 3: bin edges into CSR order -------------------------
__global__ __launch_bounds__(256) void bin_edges(
    const int* __restrict__ rows0, const int* __restrict__ cols0, const float* __restrict__ vals0,
    const int* __restrict__ rows1, const int* __restrict__ cols1, const float* __restrict__ vals1,
    int* __restrict__ cursor, int2* __restrict__ edges, int E) {
    int gid = blockIdx.x * 256 + threadIdx.x;
    int r, c; float v;
    if (gid < E)          { r = rows0[gid]; c = cols0[gid]; v = vals0[gid]; }
    else if (gid < 2 * E) { int e = gid - E; r = rows1[e]; c = cols1[e]; v = vals1[e]; }
    else return;
    int pos = atomicAdd(&cursor[r], 1);
    edges[pos] = make_int2(c, __float_as_int(v));
}

// ---------------- step 4: pull — one wave per row, plain store -------------
__global__ __launch_bounds__(256) void pull_rows(const float* __restrict__ support,
                                                 const int* __restrict__ rowptr,
                                                 const int2* __restrict__ edges,
                                                 const float* __restrict__ bias,
                                                 float* __restrict__ out, int n) {
    int wid = (blockIdx.x * 256 + threadIdx.x) >> 6;   // one wave per row
    int lane = threadIdx.x & 63;
    if (wid >= n) return;
    int s = rowptr[wid];
    int e = rowptr[wid + 1];
    float2 acc = make_float2(0.f, 0.f);
    int i = s;
    for (; i + 1 < e; i += 2) {       // 2 independent gathers in flight
        int2 cv0 = edges[i];
        int2 cv1 = edges[i + 1];
        float2 s0 = *(const float2*)(support + (size_t)cv0.x * FDIM + lane * 2);
        float2 s1 = *(const float2*)(support + (size_t)cv1.x * FDIM + lane * 2);
        float v0 = __int_as_float(cv0.y);
        float v1 = __int_as_float(cv1.y);
        acc.x += s0.x * v0 + s1.x * v1;
        acc.y += s0.y * v0 + s1.y * v1;
    }
    if (i < e) {
        int2 cv = edges[i];
        float2 sv = *(const float2*)(support + (size_t)cv.x * FDIM + lane * 2);
        float v = __int_as_float(cv.y);
        acc.x += sv.x * v;
        acc.y += sv.y * v;
    }
    float2 b = *(const float2*)(bias + lane * 2);
    *(float2*)(out + (size_t)wid * FDIM + lane * 2) =
        make_float2(acc.x + b.x, acc.y + b.y);
}

// ---------------- fallback (ws too small): old atomic scatter --------------
__global__ __launch_bounds__(256) void init_bias(const float* __restrict__ bias,
                                                 float* __restrict__ out, int n) {
    int idx = blockIdx.x * 256 + threadIdx.x;
    int total = n * (FDIM / 4);
    if (idx < total) {
        int j = (idx & (FDIM / 4 - 1)) * 4;
        float4 b = *(const float4*)(bias + j);
        *(float4*)(out + (size_t)idx * 4) = b;
    }
}

__global__ __launch_bounds__(256) void scatter_edges(
    const float* __restrict__ support,
    const int* __restrict__ rows0, const int* __restrict__ cols0, const float* __restrict__ vals0,
    const int* __restrict__ rows1, const int* __restrict__ cols1, const float* __restrict__ vals1,
    float* __restrict__ out, int E) {
    int gid = blockIdx.x * 256 + threadIdx.x;
    int lane = gid & 63;
    int eg = gid >> 6;
    if (eg >= 2 * E) return;
    const int* rows; const int* cols; const float* vals; int e;
    if (eg < E) { e = eg;     rows = rows0; cols = cols0; vals = vals0; }
    else        { e = eg - E; rows = rows1; cols = cols1; vals = vals1; }
    int r = rows[e];
    int c = cols[e];
    float v = vals[e];
    float2 s = *(const float2*)(support + (size_t)c * FDIM + lane * 2);
    float* op = out + (size_t)r * FDIM + lane * 2;
    atomicAdd(op,     s.x * v);
    atomicAdd(op + 1, s.y * v);
}

static inline size_t align256(size_t v) { return (v + 255) & ~(size_t)255; }

extern "C" void kernel_launch(void* const* d_in, const int* in_sizes, int n_in,
                              void* d_out, int out_size, void* d_ws, size_t ws_size,
                              hipStream_t stream) {
    const float* x     = (const float*)d_in[0];
    const float* w     = (const float*)d_in[1];
    const float* bias  = (const float*)d_in[2];
    const float* vals0 = (const float*)d_in[3];
    const float* vals1 = (const float*)d_in[4];
    const int*   rows0 = (const int*)d_in[5];
    const int*   cols0 = (const int*)d_in[6];
    const int*   rows1 = (const int*)d_in[7];
    const int*   cols1 = (const int*)d_in[8];
    const int n = in_sizes[0] / FDIM;
    const int E = in_sizes[3];
    float* out = (float*)d_out;

    // workspace layout
    size_t off = 0;
    float* support = (float*)((char*)d_ws + off);           off = align256(off + (size_t)n * FDIM * 4);
    int*   counts  = (int*)((char*)d_ws + off);             off = align256(off + (size_t)n * 4);
    int*   rowptr  = (int*)((char*)d_ws + off);             off = align256(off + (size_t)(n + 1) * 4);
    int*   cursor  = (int*)((char*)d_ws + off);             off = align256(off + (size_t)n * 4);
    int2*  edges   = (int2*)((char*)d_ws + off);            off = align256(off + (size_t)2 * E * 8);

    dim3 ggrid((n + 63) / 64, 2);
    gemm_xw<<<ggrid, 256, 0, stream>>>(x, w, support, n);

    if (off <= ws_size) {
        // CSR pull path
        hipMemsetAsync(counts, 0, (size_t)n * 4, stream);
        int eb = (2 * E + 255) / 256;
        hist_rows<<<eb, 256, 0, stream>>>(rows0, rows1, counts, E);
        scan_counts<<<1, 1024, 0, stream>>>(counts, rowptr, cursor, n);
        bin_edges<<<eb, 256, 0, stream>>>(rows0, cols0, vals0, rows1, cols1, vals1,
                                          cursor, edges, E);
        pull_rows<<<(n + 3) / 4, 256, 0, stream>>>(support, rowptr, edges, bias, out, n);
    } else {
        // fallback: atomic scatter
        int total4 = n * (FDIM / 4);
        init_bias<<<(total4 + 255) / 256, 256, 0, stream>>>(bias, out, n);
        long long tthreads = 2LL * E * 64;
        int blocks = (int)((tthreads + 255) / 256);
        scatter_edges<<<blocks, 256, 0, stream>>>(support, rows0, cols0, vals0,
                                                  rows1, cols1, vals1, out, E);
    }
}

// Round 3
// 413.399 us; speedup vs baseline: 2.7837x; 1.5057x over previous
//
#include <hip/hip_runtime.h>

// GConv: out = spmm(A0, S) + spmm(A1, S) + bias,  S = x @ W
// N=100000, E=600000, F_IN=F_OUT=128.
// Pull-mode SpMM via on-device CSR build; 3-phase device-wide scan
// (R2's single-block scan was 230us @ 0.15% occupancy).

#define FDIM 128
#define SCAN_TILE 2048   // 256 threads x 8 elements

// ---------------- GEMM: support = x @ W ----------------
__global__ __launch_bounds__(256) void gemm_xw(const float* __restrict__ x,
                                               const float* __restrict__ w,
                                               float* __restrict__ support, int n) {
    __shared__ float xs[64][132];
    __shared__ float ws[128][68];
    const int tid = threadIdx.x;
    const int m0 = blockIdx.x * 64;
    const int j0 = blockIdx.y * 64;

    for (int idx = tid * 4; idx < 128 * 64; idx += 256 * 4) {
        int k = idx >> 6;
        int c = idx & 63;
        float4 v = *(const float4*)(w + k * FDIM + j0 + c);
        ws[k][c] = v.x; ws[k][c + 1] = v.y; ws[k][c + 2] = v.z; ws[k][c + 3] = v.w;
    }
    for (int idx = tid * 4; idx < 64 * 128; idx += 256 * 4) {
        int r = idx >> 7;
        int c = idx & 127;
        float4 v = make_float4(0.f, 0.f, 0.f, 0.f);
        if (m0 + r < n) v = *(const float4*)(x + (size_t)(m0 + r) * FDIM + c);
        xs[r][c] = v.x; xs[r][c + 1] = v.y; xs[r][c + 2] = v.z; xs[r][c + 3] = v.w;
    }
    __syncthreads();

    const int tx = tid & 15;
    const int ty = tid >> 4;
    float acc[4][4] = {};
    #pragma unroll 4
    for (int k = 0; k < 128; ++k) {
        float4 wv = *(const float4*)&ws[k][tx * 4];
        float xv[4];
        #pragma unroll
        for (int i = 0; i < 4; ++i) xv[i] = xs[ty * 4 + i][k];
        #pragma unroll
        for (int i = 0; i < 4; ++i) {
            acc[i][0] += xv[i] * wv.x;
            acc[i][1] += xv[i] * wv.y;
            acc[i][2] += xv[i] * wv.z;
            acc[i][3] += xv[i] * wv.w;
        }
    }
    #pragma unroll
    for (int i = 0; i < 4; ++i) {
        int m = m0 + ty * 4 + i;
        if (m < n) {
            float4 v = make_float4(acc[i][0], acc[i][1], acc[i][2], acc[i][3]);
            *(float4*)(support + (size_t)m * FDIM + j0 + tx * 4) = v;
        }
    }
}

// ---------------- CSR build step 1: histogram of destination rows ----------
__global__ __launch_bounds__(256) void hist_rows(const int* __restrict__ rows0,
                                                 const int* __restrict__ rows1,
                                                 int* __restrict__ counts, int E) {
    int gid = blockIdx.x * 256 + threadIdx.x;
    if (gid < E)          atomicAdd(&counts[rows0[gid]], 1);
    else if (gid < 2 * E) atomicAdd(&counts[rows1[gid - E]], 1);
}

// ---------------- step 2: 3-phase device-wide exclusive scan ---------------
__global__ __launch_bounds__(256) void scan_p1(const int* __restrict__ counts,
                                               int* __restrict__ blockSums, int n) {
    __shared__ int sdata[256];
    const int t = threadIdx.x;
    const int base = blockIdx.x * SCAN_TILE + t * 8;
    int sum = 0;
    #pragma unroll
    for (int i = 0; i < 8; ++i) {
        int idx = base + i;
        if (idx < n) sum += counts[idx];
    }
    sdata[t] = sum;
    __syncthreads();
    for (int d = 128; d > 0; d >>= 1) {
        if (t < d) sdata[t] += sdata[t + d];
        __syncthreads();
    }
    if (t == 0) blockSums[blockIdx.x] = sdata[0];
}

// single block: exclusive-scan blockSums in place; write rowptr[n]=total
__global__ __launch_bounds__(512) void scan_p2(int* __restrict__ blockSums,
                                               int* __restrict__ rowptr,
                                               int nb, int n) {
    __shared__ int sdata[512];
    const int t = threadIdx.x;
    int v = (t < nb) ? blockSums[t] : 0;
    sdata[t] = v;
    __syncthreads();
    for (int d = 1; d < 512; d <<= 1) {
        int u = (t >= d) ? sdata[t - d] : 0;
        __syncthreads();
        sdata[t] += u;
        __syncthreads();
    }
    if (t < nb) blockSums[t] = sdata[t] - v;      // exclusive
    if (t == 511) rowptr[n] = sdata[511];          // grand total
}

__global__ __launch_bounds__(256) void scan_p3(const int* __restrict__ counts,
                                               const int* __restrict__ blockSums,
                                               int* __restrict__ rowptr,
                                               int* __restrict__ cursor, int n) {
    __shared__ int sdata[256];
    const int t = threadIdx.x;
    const int base = blockIdx.x * SCAN_TILE + t * 8;
    int loc[8];
    int sum = 0;
    #pragma unroll
    for (int i = 0; i < 8; ++i) {
        int idx = base + i;
        int c = (idx < n) ? counts[idx] : 0;
        loc[i] = sum;
        sum += c;
    }
    sdata[t] = sum;
    __syncthreads();
    const int mine = sum;
    for (int d = 1; d < 256; d <<= 1) {
        int u = (t >= d) ? sdata[t - d] : 0;
        __syncthreads();
        sdata[t] += u;
        __syncthreads();
    }
    const int off = sdata[t] - mine + blockSums[blockIdx.x];
    #pragma unroll
    for (int i = 0; i < 8; ++i) {
        int idx = base + i;
        if (idx < n) {
            int v = off + loc[i];
            rowptr[idx] = v;
            cursor[idx] = v;
        }
    }
}

// ---------------- step 3: bin edges into CSR order -------------------------
__global__ __launch_bounds__(256) void bin_edges(
    const int* __restrict__ rows0, const int* __restrict__ cols0, const float* __restrict__ vals0,
    const int* __restrict__ rows1, const int* __restrict__ cols1, const float* __restrict__ vals1,
    int* __restrict__ cursor, int2* __restrict__ edges, int E) {
    int gid = blockIdx.x * 256 + threadIdx.x;
    int r, c; float v;
    if (gid < E)          { r = rows0[gid]; c = cols0[gid]; v = vals0[gid]; }
    else if (gid < 2 * E) { int e = gid - E; r = rows1[e]; c = cols1[e]; v = vals1[e]; }
    else return;
    int pos = atomicAdd(&cursor[r], 1);
    edges[pos] = make_int2(c, __float_as_int(v));
}

// ---------------- step 4: pull — one wave per row, plain store -------------
__global__ __launch_bounds__(256) void pull_rows(const float* __restrict__ support,
                                                 const int* __restrict__ rowptr,
                                                 const int2* __restrict__ edges,
                                                 const float* __restrict__ bias,
                                                 float* __restrict__ out, int n) {
    int wid = (blockIdx.x * 256 + threadIdx.x) >> 6;
    int lane = threadIdx.x & 63;
    if (wid >= n) return;
    int s = rowptr[wid];
    int e = rowptr[wid + 1];
    float2 acc = make_float2(0.f, 0.f);
    int i = s;
    for (; i + 1 < e; i += 2) {
        int2 cv0 = edges[i];
        int2 cv1 = edges[i + 1];
        float2 s0 = *(const float2*)(support + (size_t)cv0.x * FDIM + lane * 2);
        float2 s1 = *(const float2*)(support + (size_t)cv1.x * FDIM + lane * 2);
        float v0 = __int_as_float(cv0.y);
        float v1 = __int_as_float(cv1.y);
        acc.x += s0.x * v0 + s1.x * v1;
        acc.y += s0.y * v0 + s1.y * v1;
    }
    if (i < e) {
        int2 cv = edges[i];
        float2 sv = *(const float2*)(support + (size_t)cv.x * FDIM + lane * 2);
        float v = __int_as_float(cv.y);
        acc.x += sv.x * v;
        acc.y += sv.y * v;
    }
    float2 b = *(const float2*)(bias + lane * 2);
    *(float2*)(out + (size_t)wid * FDIM + lane * 2) =
        make_float2(acc.x + b.x, acc.y + b.y);
}

// ---------------- fallback (ws too small): old atomic scatter --------------
__global__ __launch_bounds__(256) void init_bias(const float* __restrict__ bias,
                                                 float* __restrict__ out, int n) {
    int idx = blockIdx.x * 256 + threadIdx.x;
    int total = n * (FDIM / 4);
    if (idx < total) {
        int j = (idx & (FDIM / 4 - 1)) * 4;
        float4 b = *(const float4*)(bias + j);
        *(float4*)(out + (size_t)idx * 4) = b;
    }
}

__global__ __launch_bounds__(256) void scatter_edges(
    const float* __restrict__ support,
    const int* __restrict__ rows0, const int* __restrict__ cols0, const float* __restrict__ vals0,
    const int* __restrict__ rows1, const int* __restrict__ cols1, const float* __restrict__ vals1,
    float* __restrict__ out, int E) {
    int gid = blockIdx.x * 256 + threadIdx.x;
    int lane = gid & 63;
    int eg = gid >> 6;
    if (eg >= 2 * E) return;
    const int* rows; const int* cols; const float* vals; int e;
    if (eg < E) { e = eg;     rows = rows0; cols = cols0; vals = vals0; }
    else        { e = eg - E; rows = rows1; cols = cols1; vals = vals1; }
    int r = rows[e];
    int c = cols[e];
    float v = vals[e];
    float2 s = *(const float2*)(support + (size_t)c * FDIM + lane * 2);
    float* op = out + (size_t)r * FDIM + lane * 2;
    atomicAdd(op,     s.x * v);
    atomicAdd(op + 1, s.y * v);
}

static inline size_t align256(size_t v) { return (v + 255) & ~(size_t)255; }

extern "C" void kernel_launch(void* const* d_in, const int* in_sizes, int n_in,
                              void* d_out, int out_size, void* d_ws, size_t ws_size,
                              hipStream_t stream) {
    const float* x     = (const float*)d_in[0];
    const float* w     = (const float*)d_in[1];
    const float* bias  = (const float*)d_in[2];
    const float* vals0 = (const float*)d_in[3];
    const float* vals1 = (const float*)d_in[4];
    const int*   rows0 = (const int*)d_in[5];
    const int*   cols0 = (const int*)d_in[6];
    const int*   rows1 = (const int*)d_in[7];
    const int*   cols1 = (const int*)d_in[8];
    const int n = in_sizes[0] / FDIM;
    const int E = in_sizes[3];
    float* out = (float*)d_out;

    const int nScanBlocks = (n + SCAN_TILE - 1) / SCAN_TILE;   // 49 for n=100k

    // workspace layout
    size_t off = 0;
    float* support  = (float*)((char*)d_ws + off);  off = align256(off + (size_t)n * FDIM * 4);
    int*   counts   = (int*)((char*)d_ws + off);    off = align256(off + (size_t)n * 4);
    int*   rowptr   = (int*)((char*)d_ws + off);    off = align256(off + (size_t)(n + 1) * 4);
    int*   cursor   = (int*)((char*)d_ws + off);    off = align256(off + (size_t)n * 4);
    int*   blockSums= (int*)((char*)d_ws + off);    off = align256(off + (size_t)nScanBlocks * 4);
    int2*  edges    = (int2*)((char*)d_ws + off);   off = align256(off + (size_t)2 * E * 8);

    dim3 ggrid((n + 63) / 64, 2);
    gemm_xw<<<ggrid, 256, 0, stream>>>(x, w, support, n);

    if (off <= ws_size && nScanBlocks <= 512) {
        // CSR pull path
        hipMemsetAsync(counts, 0, (size_t)n * 4, stream);
        int eb = (2 * E + 255) / 256;
        hist_rows<<<eb, 256, 0, stream>>>(rows0, rows1, counts, E);
        scan_p1<<<nScanBlocks, 256, 0, stream>>>(counts, blockSums, n);
        scan_p2<<<1, 512, 0, stream>>>(blockSums, rowptr, nScanBlocks, n);
        scan_p3<<<nScanBlocks, 256, 0, stream>>>(counts, blockSums, rowptr, cursor, n);
        bin_edges<<<eb, 256, 0, stream>>>(rows0, cols0, vals0, rows1, cols1, vals1,
                                          cursor, edges, E);
        pull_rows<<<(n + 3) / 4, 256, 0, stream>>>(support, rowptr, edges, bias, out, n);
    } else {
        // fallback: atomic scatter
        int total4 = n * (FDIM / 4);
        init_bias<<<(total4 + 255) / 256, 256, 0, stream>>>(bias, out, n);
        long long tthreads = 2LL * E * 64;
        int blocks = (int)((tthreads + 255) / 256);
        scatter_edges<<<blocks, 256, 0, stream>>>(support, rows0, cols0, vals0,
                                                  rows1, cols1, vals1, out, E);
    }
}

// Round 4
// 343.565 us; speedup vs baseline: 3.3495x; 1.2033x over previous
//
#include <hip/hip_runtime.h>

// GConv: out = spmm(A0, S) + spmm(A1, S) + bias,  S = x @ W
// N=100000, E=600000, F_IN=F_OUT=128.
// R4: (1) CSR build (hist+scan+bin, ~130us, 8x write-amplified scatter)
//     replaced by per-row linked list via atomicExch — coalesced next[] writes.
//     (2) GEMM -> bf16 MFMA (16x16x32), support stored bf16 -> pull gather halves.

#define FDIM 128

typedef __attribute__((ext_vector_type(8))) short short8;
typedef __attribute__((ext_vector_type(4))) float floatx4;

__device__ __forceinline__ unsigned short f32_to_bf16(float f) {
    unsigned int u = __float_as_uint(f);
    unsigned int r = u + 0x7fffu + ((u >> 16) & 1u);   // round-to-nearest-even
    return (unsigned short)(r >> 16);
}

// ---------------- GEMM: support(bf16) = x @ W via MFMA ---------------------
// Tile: 64 rows x 128 cols per block, K=128 fully unrolled.
// LDS: As 64x136 bf16 (pad 8 keeps 16B align + breaks bank stride) + Bs 128x136.
__global__ __launch_bounds__(256) void gemm_mfma(const float* __restrict__ x,
                                                 const float* __restrict__ w,
                                                 unsigned short* __restrict__ support,
                                                 int n) {
    __shared__ __align__(16) short As[64][136];    // As[m][k]
    __shared__ __align__(16) short Bs[128][136];   // Bs[n][k] = W[k][n] transposed
    const int tid = threadIdx.x;
    const int m0 = blockIdx.x * 64;

    // stage x tile -> bf16 LDS (row-major m,k)
    #pragma unroll
    for (int i = 0; i < 8; ++i) {
        int idx = tid + i * 256;          // 0..2047 float4s
        int r = idx >> 5, c4 = idx & 31;
        float4 v = make_float4(0.f, 0.f, 0.f, 0.f);
        if (m0 + r < n) v = *(const float4*)(x + (size_t)(m0 + r) * FDIM + c4 * 4);
        short4 s;
        s.x = (short)f32_to_bf16(v.x); s.y = (short)f32_to_bf16(v.y);
        s.z = (short)f32_to_bf16(v.z); s.w = (short)f32_to_bf16(v.w);
        *(short4*)&As[r][c4 * 4] = s;
    }
    // stage W -> bf16 LDS transposed (n-major, k contiguous)
    #pragma unroll
    for (int i = 0; i < 16; ++i) {
        int idx = tid + i * 256;          // 0..4095 float4s
        int k = idx >> 5, c4 = idx & 31;
        float4 v = *(const float4*)(w + (size_t)k * FDIM + c4 * 4);
        Bs[c4 * 4 + 0][k] = (short)f32_to_bf16(v.x);
        Bs[c4 * 4 + 1][k] = (short)f32_to_bf16(v.y);
        Bs[c4 * 4 + 2][k] = (short)f32_to_bf16(v.z);
        Bs[c4 * 4 + 3][k] = (short)f32_to_bf16(v.w);
    }
    __syncthreads();

    const int wv = tid >> 6;          // wave 0..3 -> rows [wv*16, wv*16+16)
    const int lane = tid & 63;
    const int quad = lane >> 4;       // 0..3
    const int lr = lane & 15;         // 0..15

    floatx4 acc[8];
    #pragma unroll
    for (int nt = 0; nt < 8; ++nt) acc[nt] = (floatx4)0.f;

    #pragma unroll
    for (int ks = 0; ks < 4; ++ks) {  // K = 4 * 32
        // A frag: A[m=lr][k=quad*8+j]
        short8 a = *(const short8*)&As[wv * 16 + lr][ks * 32 + quad * 8];
        #pragma unroll
        for (int nt = 0; nt < 8; ++nt) {
            // B frag: B[k=quad*8+j][n=lr]  (k-contiguous in Bs[n][k])
            short8 b = *(const short8*)&Bs[nt * 16 + lr][ks * 32 + quad * 8];
            acc[nt] = __builtin_amdgcn_mfma_f32_16x16x32_bf16(a, b, acc[nt], 0, 0, 0);
        }
    }

    // epilogue: C/D layout col=lr, row=quad*4+i
    #pragma unroll
    for (int i = 0; i < 4; ++i) {
        int row = m0 + wv * 16 + quad * 4 + i;
        if (row < n) {
            #pragma unroll
            for (int nt = 0; nt < 8; ++nt)
                support[(size_t)row * FDIM + nt * 16 + lr] = f32_to_bf16(acc[nt][i]);
        }
    }
}

// ---------------- linked-list build: head[r] -> chain of edge ids ----------
__global__ __launch_bounds__(256) void build_list(const int* __restrict__ rows0,
                                                  const int* __restrict__ rows1,
                                                  int* __restrict__ head,
                                                  int* __restrict__ next, int E) {
    int gid = blockIdx.x * 256 + threadIdx.x;
    if (gid >= 2 * E) return;
    int r = (gid < E) ? rows0[gid] : rows1[gid - E];
    int old = atomicExch(&head[r], gid);
    next[gid] = old;   // safe: next[] only read by the later pull kernel
}

// ---------------- pull: one wave per row walks its chain -------------------
__global__ __launch_bounds__(256) void pull_ll(const unsigned short* __restrict__ support,
                                               const int* __restrict__ head,
                                               const int* __restrict__ next,
                                               const int* __restrict__ cols0,
                                               const float* __restrict__ vals0,
                                               const int* __restrict__ cols1,
                                               const float* __restrict__ vals1,
                                               const float* __restrict__ bias,
                                               float* __restrict__ out, int n, int E) {
    int wid = (blockIdx.x * 256 + threadIdx.x) >> 6;
    int lane = threadIdx.x & 63;
    if (wid >= n) return;
    float ax = 0.f, ay = 0.f;
    int e = head[wid];                 // wave-uniform chain walk
    while (e >= 0) {
        int nx = next[e];
        int c; float v;
        if (e < E) { c = cols0[e]; v = vals0[e]; }
        else       { c = cols1[e - E]; v = vals1[e - E]; }
        unsigned int u = *(const unsigned int*)(support + (size_t)c * FDIM + lane * 2);
        float sx = __uint_as_float((u & 0xffffu) << 16);
        float sy = __uint_as_float(u & 0xffff0000u);
        ax += v * sx;
        ay += v * sy;
        e = nx;
    }
    float2 b = *(const float2*)(bias + lane * 2);
    *(float2*)(out + (size_t)wid * FDIM + lane * 2) = make_float2(ax + b.x, ay + b.y);
}

// ---------------- fallback (ws too small): atomic scatter ------------------
__global__ __launch_bounds__(256) void init_bias(const float* __restrict__ bias,
                                                 float* __restrict__ out, int n) {
    int idx = blockIdx.x * 256 + threadIdx.x;
    int total = n * (FDIM / 4);
    if (idx < total) {
        int j = (idx & (FDIM / 4 - 1)) * 4;
        float4 b = *(const float4*)(bias + j);
        *(float4*)(out + (size_t)idx * 4) = b;
    }
}

__global__ __launch_bounds__(256) void scatter_bf16(
    const unsigned short* __restrict__ support,
    const int* __restrict__ rows0, const int* __restrict__ cols0, const float* __restrict__ vals0,
    const int* __restrict__ rows1, const int* __restrict__ cols1, const float* __restrict__ vals1,
    float* __restrict__ out, int E) {
    int gid = blockIdx.x * 256 + threadIdx.x;
    int lane = gid & 63;
    int eg = gid >> 6;
    if (eg >= 2 * E) return;
    int r, c; float v;
    if (eg < E) { r = rows0[eg]; c = cols0[eg]; v = vals0[eg]; }
    else        { int e = eg - E; r = rows1[e]; c = cols1[e]; v = vals1[e]; }
    unsigned int u = *(const unsigned int*)(support + (size_t)c * FDIM + lane * 2);
    float sx = __uint_as_float((u & 0xffffu) << 16);
    float sy = __uint_as_float(u & 0xffff0000u);
    float* op = out + (size_t)r * FDIM + lane * 2;
    atomicAdd(op,     sx * v);
    atomicAdd(op + 1, sy * v);
}

static inline size_t align256(size_t v) { return (v + 255) & ~(size_t)255; }

extern "C" void kernel_launch(void* const* d_in, const int* in_sizes, int n_in,
                              void* d_out, int out_size, void* d_ws, size_t ws_size,
                              hipStream_t stream) {
    const float* x     = (const float*)d_in[0];
    const float* w     = (const float*)d_in[1];
    const float* bias  = (const float*)d_in[2];
    const float* vals0 = (const float*)d_in[3];
    const float* vals1 = (const float*)d_in[4];
    const int*   rows0 = (const int*)d_in[5];
    const int*   cols0 = (const int*)d_in[6];
    const int*   rows1 = (const int*)d_in[7];
    const int*   cols1 = (const int*)d_in[8];
    const int n = in_sizes[0] / FDIM;
    const int E = in_sizes[3];
    float* out = (float*)d_out;

    // workspace: support (bf16) + head + next
    size_t off = 0;
    unsigned short* support = (unsigned short*)((char*)d_ws + off);
    off = align256(off + (size_t)n * FDIM * 2);
    int* head = (int*)((char*)d_ws + off);  off = align256(off + (size_t)n * 4);
    int* next = (int*)((char*)d_ws + off);  off = align256(off + (size_t)2 * E * 4);

    gemm_mfma<<<(n + 63) / 64, 256, 0, stream>>>(x, w, support, n);

    if (off <= ws_size) {
        hipMemsetAsync(head, 0xFF, (size_t)n * 4, stream);   // head = -1
        int eb = (2 * E + 255) / 256;
        build_list<<<eb, 256, 0, stream>>>(rows0, rows1, head, next, E);
        pull_ll<<<(n + 3) / 4, 256, 0, stream>>>(support, head, next,
                                                 cols0, vals0, cols1, vals1,
                                                 bias, out, n, E);
    } else {
        int total4 = n * (FDIM / 4);
        init_bias<<<(total4 + 255) / 256, 256, 0, stream>>>(bias, out, n);
        long long tthreads = 2LL * E * 64;
        int blocks = (int)((tthreads + 255) / 256);
        scatter_bf16<<<blocks, 256, 0, stream>>>(support, rows0, cols0, vals0,
                                                 rows1, cols1, vals1, out, E);
    }
}

// Round 5
// 312.480 us; speedup vs baseline: 3.6827x; 1.0995x over previous
//
#include <hip/hip_runtime.h>

// GConv: out = spmm(A0, S) + spmm(A1, S) + bias,  S = x @ W
// N=100000, E=600000, F_IN=F_OUT=128.
// R5: (1) chain metadata packed into one int4 record (next,col,val) ->
//     1 scattered line per edge step instead of 3 (R4: 230MB metadata fetch).
//     (2) W^T precomputed to bf16 once; gemm stages As/Bs as straight
//     coalesced copies (R4 transposed W in-kernel: scalar 2B LDS writes at
//     bank-stride 16 -> 16-way conflicts, ~150us).

#define FDIM 128

typedef __attribute__((ext_vector_type(8))) short short8;
typedef __attribute__((ext_vector_type(4))) float floatx4;

__device__ __forceinline__ unsigned short f32_to_bf16(float f) {
    unsigned int u = __float_as_uint(f);
    unsigned int r = u + 0x7fffu + ((u >> 16) & 1u);   // RNE
    return (unsigned short)(r >> 16);
}

// ---------------- Wt[n][k] = bf16(W[k][n]) — 64KB, one-shot ----------------
__global__ __launch_bounds__(256) void wt_conv(const float* __restrict__ w,
                                               unsigned short* __restrict__ wt) {
    int idx = blockIdx.x * 256 + threadIdx.x;   // 0..16383
    int nn = idx >> 7, k = idx & 127;
    wt[idx] = f32_to_bf16(w[(size_t)k * FDIM + nn]);
}

// ---------------- GEMM: support(bf16) = x @ W via MFMA ---------------------
// 64 rows x 128 cols per block; As/Bs staged with coalesced 16B copies.
__global__ __launch_bounds__(256) void gemm_mfma(const float* __restrict__ x,
                                                 const unsigned short* __restrict__ wt,
                                                 unsigned short* __restrict__ support,
                                                 int n) {
    __shared__ __align__(16) short As[64][136];    // As[m][k], pitch 272B (16B-aligned)
    __shared__ __align__(16) short Bs[128][136];   // Bs[n][k]
    const int tid = threadIdx.x;
    const int m0 = blockIdx.x * 64;

    // stage x tile -> bf16 (coalesced float4 reads, short4 writes, lane stride 8B)
    #pragma unroll
    for (int i = 0; i < 8; ++i) {
        int idx = tid + i * 256;          // 0..2047 float4 chunks
        int r = idx >> 5, c4 = idx & 31;
        float4 v = make_float4(0.f, 0.f, 0.f, 0.f);
        if (m0 + r < n) v = *(const float4*)(x + (size_t)(m0 + r) * FDIM + c4 * 4);
        short4 s;
        s.x = (short)f32_to_bf16(v.x); s.y = (short)f32_to_bf16(v.y);
        s.z = (short)f32_to_bf16(v.z); s.w = (short)f32_to_bf16(v.w);
        *(short4*)&As[r][c4 * 4] = s;
    }
    // stage Wt -> Bs: straight copy, coalesced 16B chunks
    #pragma unroll
    for (int i = 0; i < 8; ++i) {
        int idx = tid + i * 256;          // 0..2047 short8 chunks
        int r = idx >> 4, c8 = idx & 15;
        short8 v = *(const short8*)(wt + (size_t)r * FDIM + c8 * 8);
        *(short8*)&Bs[r][c8 * 8] = v;
    }
    __syncthreads();

    const int wv = tid >> 6;          // wave 0..3 -> rows [wv*16, wv*16+16)
    const int lane = tid & 63;
    const int quad = lane >> 4;
    const int lr = lane & 15;

    floatx4 acc[8];
    #pragma unroll
    for (int nt = 0; nt < 8; ++nt) acc[nt] = (floatx4)0.f;

    #pragma unroll
    for (int ks = 0; ks < 4; ++ks) {
        short8 a = *(const short8*)&As[wv * 16 + lr][ks * 32 + quad * 8];
        #pragma unroll
        for (int nt = 0; nt < 8; ++nt) {
            short8 b = *(const short8*)&Bs[nt * 16 + lr][ks * 32 + quad * 8];
            acc[nt] = __builtin_amdgcn_mfma_f32_16x16x32_bf16(a, b, acc[nt], 0, 0, 0);
        }
    }

    // epilogue: C/D layout col=lr, row=quad*4+i
    #pragma unroll
    for (int i = 0; i < 4; ++i) {
        int row = m0 + wv * 16 + quad * 4 + i;
        if (row < n) {
            #pragma unroll
            for (int nt = 0; nt < 8; ++nt)
                support[(size_t)row * FDIM + nt * 16 + lr] = f32_to_bf16(acc[nt][i]);
        }
    }
}

// ---------------- build: head[r] -> chain; rec[e]=(next,col,val) coalesced --
__global__ __launch_bounds__(256) void build_rec(const int* __restrict__ rows0,
                                                 const int* __restrict__ cols0,
                                                 const float* __restrict__ vals0,
                                                 const int* __restrict__ rows1,
                                                 const int* __restrict__ cols1,
                                                 const float* __restrict__ vals1,
                                                 int* __restrict__ head,
                                                 int4* __restrict__ rec, int E) {
    int gid = blockIdx.x * 256 + threadIdx.x;
    if (gid >= 2 * E) return;
    int r, c; float v;
    if (gid < E) { r = rows0[gid]; c = cols0[gid]; v = vals0[gid]; }
    else         { int e = gid - E; r = rows1[e]; c = cols1[e]; v = vals1[e]; }
    int old = atomicExch(&head[r], gid);
    rec[gid] = make_int4(old, c, __float_as_int(v), 0);
}

// ---------------- pull: one wave per row; 1 packed load per chain step -----
__global__ __launch_bounds__(256) void pull_rec(const unsigned short* __restrict__ support,
                                                const int* __restrict__ head,
                                                const int4* __restrict__ rec,
                                                const float* __restrict__ bias,
                                                float* __restrict__ out, int n) {
    int wid = (blockIdx.x * 256 + threadIdx.x) >> 6;
    int lane = threadIdx.x & 63;
    if (wid >= n) return;
    float ax = 0.f, ay = 0.f;
    int e = head[wid];                 // wave-uniform chain walk
    while (e >= 0) {
        int4 rc = rec[e];              // broadcast load: (next, col, val, -)
        float v = __int_as_float(rc.z);
        unsigned int u = *(const unsigned int*)(support + (size_t)rc.y * FDIM + lane * 2);
        ax += v * __uint_as_float((u & 0xffffu) << 16);
        ay += v * __uint_as_float(u & 0xffff0000u);
        e = rc.x;
    }
    float2 b = *(const float2*)(bias + lane * 2);
    *(float2*)(out + (size_t)wid * FDIM + lane * 2) = make_float2(ax + b.x, ay + b.y);
}

// ---------------- fallback (ws too small): atomic scatter ------------------
__global__ __launch_bounds__(256) void init_bias(const float* __restrict__ bias,
                                                 float* __restrict__ out, int n) {
    int idx = blockIdx.x * 256 + threadIdx.x;
    int total = n * (FDIM / 4);
    if (idx < total) {
        int j = (idx & (FDIM / 4 - 1)) * 4;
        float4 b = *(const float4*)(bias + j);
        *(float4*)(out + (size_t)idx * 4) = b;
    }
}

__global__ __launch_bounds__(256) void scatter_bf16(
    const unsigned short* __restrict__ support,
    const int* __restrict__ rows0, const int* __restrict__ cols0, const float* __restrict__ vals0,
    const int* __restrict__ rows1, const int* __restrict__ cols1, const float* __restrict__ vals1,
    float* __restrict__ out, int E) {
    int gid = blockIdx.x * 256 + threadIdx.x;
    int lane = gid & 63;
    int eg = gid >> 6;
    if (eg >= 2 * E) return;
    int r, c; float v;
    if (eg < E) { r = rows0[eg]; c = cols0[eg]; v = vals0[eg]; }
    else        { int e = eg - E; r = rows1[e]; c = cols1[e]; v = vals1[e]; }
    unsigned int u = *(const unsigned int*)(support + (size_t)c * FDIM + lane * 2);
    float sx = __uint_as_float((u & 0xffffu) << 16);
    float sy = __uint_as_float(u & 0xffff0000u);
    float* op = out + (size_t)r * FDIM + lane * 2;
    atomicAdd(op,     sx * v);
    atomicAdd(op + 1, sy * v);
}

static inline size_t align256(size_t v) { return (v + 255) & ~(size_t)255; }

extern "C" void kernel_launch(void* const* d_in, const int* in_sizes, int n_in,
                              void* d_out, int out_size, void* d_ws, size_t ws_size,
                              hipStream_t stream) {
    const float* x     = (const float*)d_in[0];
    const float* w     = (const float*)d_in[1];
    const float* bias  = (const float*)d_in[2];
    const float* vals0 = (const float*)d_in[3];
    const float* vals1 = (const float*)d_in[4];
    const int*   rows0 = (const int*)d_in[5];
    const int*   cols0 = (const int*)d_in[6];
    const int*   rows1 = (const int*)d_in[7];
    const int*   cols1 = (const int*)d_in[8];
    const int n = in_sizes[0] / FDIM;
    const int E = in_sizes[3];
    float* out = (float*)d_out;

    size_t off = 0;
    unsigned short* support = (unsigned short*)((char*)d_ws + off);
    off = align256(off + (size_t)n * FDIM * 2);
    unsigned short* wt = (unsigned short*)((char*)d_ws + off);
    off = align256(off + (size_t)FDIM * FDIM * 2);
    int*  head = (int*)((char*)d_ws + off);   off = align256(off + (size_t)n * 4);
    int4* rec  = (int4*)((char*)d_ws + off);  off = align256(off + (size_t)2 * E * 16);

    wt_conv<<<(FDIM * FDIM) / 256, 256, 0, stream>>>(w, wt);
    gemm_mfma<<<(n + 63) / 64, 256, 0, stream>>>(x, wt, support, n);

    if (off <= ws_size) {
        hipMemsetAsync(head, 0xFF, (size_t)n * 4, stream);   // head = -1
        int eb = (2 * E + 255) / 256;
        build_rec<<<eb, 256, 0, stream>>>(rows0, cols0, vals0, rows1, cols1, vals1,
                                          head, rec, E);
        pull_rec<<<(n + 3) / 4, 256, 0, stream>>>(support, head, rec, bias, out, n);
    } else {
        int total4 = n * (FDIM / 4);
        init_bias<<<(total4 + 255) / 256, 256, 0, stream>>>(bias, out, n);
        long long tthreads = 2LL * E * 64;
        int blocks = (int)((tthreads + 255) / 256);
        scatter_bf16<<<blocks, 256, 0, stream>>>(support, rows0, cols0, vals0,
                                                 rows1, cols1, vals1, out, E);
    }
}